// Round 8
// baseline (255.978 us; speedup 1.0000x reference)
//
#include <hip/hip_runtime.h>
#include <hip/hip_bf16.h>
#include <hip/hip_fp16.h>

#define NN 100000
#define DIM 128
#define NB 391            // dst buckets of 256 nodes: (NN+255)>>8
#define BCAP 5120         // bucket capacity: lambda=4096, +16 sigma
#define GTILES ((NN + 63) / 64)   // 1563 row-tiles (64 rows each)

typedef _Float16 f16x8 __attribute__((ext_vector_type(8)));
typedef float f32x4 __attribute__((ext_vector_type(4)));

// ---------------- tiny zero ----------------
__global__ void k_zero(int* __restrict__ p, int n) {
    int i = blockIdx.x * blockDim.x + threadIdx.x;
    if (i < n) p[i] = 0;
}

// ---------------- Phase A: bin edges by dst>>8, packed src|(dst&255)<<17 ----------------
__global__ void k_binA(const int* __restrict__ src, const int* __restrict__ dst,
                       int* __restrict__ bcur, int* __restrict__ binbuf, int E) {
    __shared__ int hist[NB];
    __shared__ int base[NB];
    const int t = threadIdx.x;
    for (int b = t; b < NB; b += 256) hist[b] = 0;
    __syncthreads();

    const int e0 = blockIdx.x * 4096;
    int mys[16], myd[16];
#pragma unroll
    for (int i = 0; i < 16; ++i) {
        const int e = e0 + i * 256 + t;
        int d = -1, s = 0;
        if (e < E) {
            d = dst[e];
            s = src[e];
            atomicAdd(&hist[d >> 8], 1);
        }
        mys[i] = s;
        myd[i] = d;
    }
    __syncthreads();

    for (int b = t; b < NB; b += 256) {
        const int h = hist[b];
        base[b] = h ? atomicAdd(&bcur[b], h) : 0;
    }
    __syncthreads();
    for (int b = t; b < NB; b += 256) hist[b] = 0;  // reuse as local cursor
    __syncthreads();

#pragma unroll
    for (int i = 0; i < 16; ++i) {
        const int d = myd[i];
        if (d >= 0) {
            const int b = d >> 8;
            const int loc = atomicAdd(&hist[b], 1);
            const int p = base[b] + loc;
            if (p < BCAP) binbuf[b * BCAP + p] = mys[i] | ((d & 255) << 17);
        }
    }
}

// ---------------- Phase B1: per-bucket degree count + dinv + bucket sum ----------------
// replaces binCount + scan1 + dinv kernels
__global__ void k_binCount(const int* __restrict__ bcur, const int* __restrict__ binbuf,
                           int* __restrict__ degi, float* __restrict__ dinv,
                           int* __restrict__ bsum) {
    __shared__ int cnt[256];
    __shared__ int red[256];
    const int b = blockIdx.x;
    const int t = threadIdx.x;
    cnt[t] = 0;
    __syncthreads();
    const int n = min(bcur[b], BCAP);
    const int* p = &binbuf[b * BCAP];
    for (int i = t; i < n; i += 256) atomicAdd(&cnt[p[i] >> 17], 1);
    __syncthreads();
    const int node = b * 256 + t;
    const int c = cnt[t];
    if (node < NN) {
        degi[node] = c;
        dinv[node] = rsqrtf((float)(c + 1));  // +1 self-loop
    }
    red[t] = (node < NN) ? c : 0;
    __syncthreads();
    for (int d = 128; d > 0; d >>= 1) {
        if (t < d) red[t] += red[t + d];
        __syncthreads();
    }
    if (t == 0) bsum[b] = red[0];
}

// ---------------- exclusive scan of bucket sums (NB <= 1024), single block ----------------
__global__ void k_scan2(int* __restrict__ bsum, int nb) {
    __shared__ int s[1024];
    const int t = threadIdx.x;
    const int v = (t < nb) ? bsum[t] : 0;
    s[t] = v;
    __syncthreads();
    int acc = v;
    for (int d = 1; d < 1024; d <<= 1) {
        const int o = (t >= d) ? s[t - d] : 0;
        __syncthreads();
        acc += o;
        s[t] = acc;
        __syncthreads();
    }
    if (t < nb) bsum[t] = acc - v;  // exclusive
}

// ---------------- GEMM1 (MFMA, fp32 x in, fp16 out) + fused CSR fill-scan blocks ----------------
// blocks [0,NB): compute rowptr for bucket (LDS scan of degi + bsum base), write rowptr,
//                then fill csr via LDS cursors.
// blocks [NB,..): hs = half((x @ W1) * dinv[row]); W frags in registers, A from global.
__global__ void k_gemm1(const float* __restrict__ inF, const float* __restrict__ W,
                        const float* __restrict__ dinv, _Float16* __restrict__ outH,
                        const int* __restrict__ degi, const int* __restrict__ bsum,
                        int* __restrict__ rowptr, const int* __restrict__ bcur,
                        const int* __restrict__ binbuf, int* __restrict__ csr) {
    __shared__ int s[256];
    __shared__ int cur[256];
    const int t = threadIdx.x;

    if (blockIdx.x < NB) {
        const int b = blockIdx.x;
        const int node = b * 256 + t;
        const int deg = (node < NN) ? degi[node] : 0;
        // exclusive scan over 256 degrees
        s[t] = deg;
        __syncthreads();
        int acc = deg;
        for (int d = 1; d < 256; d <<= 1) {
            const int o = (t >= d) ? s[t - d] : 0;
            __syncthreads();
            acc += o;
            s[t] = acc;
            __syncthreads();
        }
        const int ex = acc - deg + bsum[b];
        cur[t] = ex;
        if (node < NN) {
            rowptr[node] = ex;
            if (node == NN - 1) rowptr[NN] = ex + deg;
        }
        __syncthreads();
        // fill
        const int n = min(bcur[b], BCAP);
        const int* p = &binbuf[b * BCAP];
        for (int i = t; i < n; i += 256) {
            const int v = p[i];
            const int pos = atomicAdd(&cur[v >> 17], 1);
            csr[pos] = v & 0x1FFFF;
        }
        return;
    }

    const int tile = blockIdx.x - NB;
    const int row0 = tile * 64;
    const int wv   = t >> 6;
    const int l    = t & 63;
    const int l15  = l & 15;
    const int lk8  = (l >> 4) << 3;
    const int colw = wv << 5;

    // wave-private W fragments
    f16x8 bf[2][4];
#pragma unroll
    for (int ct = 0; ct < 2; ++ct)
#pragma unroll
        for (int kt = 0; kt < 4; ++kt) {
            const int nn = colw + ct * 16 + l15;
            const int k0 = kt * 32 + lk8;
            f16x8 v;
#pragma unroll
            for (int j = 0; j < 8; ++j) v[j] = (_Float16)W[(k0 + j) * DIM + nn];
            bf[ct][kt] = v;
        }

    f32x4 acc[4][2];
#pragma unroll
    for (int rt = 0; rt < 4; ++rt)
#pragma unroll
        for (int ct = 0; ct < 2; ++ct) acc[rt][ct] = (f32x4){0.f, 0.f, 0.f, 0.f};

#pragma unroll
    for (int rt = 0; rt < 4; ++rt) {
        int row = row0 + rt * 16 + l15;
        row = min(row, NN - 1);
        f16x8 a[4];
#pragma unroll
        for (int kt = 0; kt < 4; ++kt) {
            const int k0 = kt * 32 + lk8;
            const float4 v0 = *(const float4*)&inF[row * DIM + k0];
            const float4 v1 = *(const float4*)&inF[row * DIM + k0 + 4];
            f16x8 v;
            v[0] = (_Float16)v0.x; v[1] = (_Float16)v0.y;
            v[2] = (_Float16)v0.z; v[3] = (_Float16)v0.w;
            v[4] = (_Float16)v1.x; v[5] = (_Float16)v1.y;
            v[6] = (_Float16)v1.z; v[7] = (_Float16)v1.w;
            a[kt] = v;
        }
#pragma unroll
        for (int ct = 0; ct < 2; ++ct)
#pragma unroll
            for (int kt = 0; kt < 4; ++kt)
                acc[rt][ct] = __builtin_amdgcn_mfma_f32_16x16x32_f16(a[kt], bf[ct][kt],
                                                                    acc[rt][ct], 0, 0, 0);
    }

#pragma unroll
    for (int rt = 0; rt < 4; ++rt)
#pragma unroll
        for (int r = 0; r < 4; ++r) {
            const int row = row0 + rt * 16 + ((l >> 4) << 2) + r;
            if (row < NN) {
                const float d = dinv[row];
                outH[row * DIM + colw + l15]      = (_Float16)(acc[rt][0][r] * d);
                outH[row * DIM + colw + 16 + l15] = (_Float16)(acc[rt][1][r] * d);
            }
        }
}

// ---------------- fused gather1 + GEMM2 ----------------
// Block = 64 dst rows. Phase 1: wave wv gathers nodes [row0+16wv, +16): fp32 accumulate
// over CSR, transform relu(dinv*acc + b1), deposit fp16 row into LDS A-tile (padded).
// Phase 2: MFMA with in-register W2 frags; hs2 = half(A@W2 * dinv[row]).
__global__ void k_gather_gemm(const __half* __restrict__ hs, const float* __restrict__ W,
                              const float* __restrict__ dinv, const float* __restrict__ b1,
                              _Float16* __restrict__ outH, const int* __restrict__ csr,
                              const int* __restrict__ rowptr) {
    __shared__ _Float16 As[64][136];   // 272 B row stride: bank-rotated, 16B-aligned
    const int t    = threadIdx.x;
    const int wv   = t >> 6;
    const int l    = t & 63;
    const int off  = l << 1;
    const int row0 = blockIdx.x * 64;

    const float2 bb = {b1[off], b1[off + 1]};

#pragma unroll 1
    for (int i = 0; i < 16; ++i) {
        const int lr = wv * 16 + i;
        const int n  = row0 + lr;
        float2 r = {0.f, 0.f};
        if (n < NN) {
            const int start = __builtin_amdgcn_readfirstlane(rowptr[n]);
            const int end   = __builtin_amdgcn_readfirstlane(rowptr[n + 1]);
            float2 a0 = __half22float2(*(const __half2*)&hs[n * DIM + off]);  // self-loop
            float2 a1 = {0.f, 0.f}, a2 = {0.f, 0.f}, a3 = {0.f, 0.f};
            int j = start;
            for (; j + 3 < end; j += 4) {
                const int s0 = __builtin_amdgcn_readfirstlane(csr[j]);
                const int s1 = __builtin_amdgcn_readfirstlane(csr[j + 1]);
                const int s2 = __builtin_amdgcn_readfirstlane(csr[j + 2]);
                const int s3 = __builtin_amdgcn_readfirstlane(csr[j + 3]);
                const float2 v0 = __half22float2(*(const __half2*)&hs[s0 * DIM + off]);
                const float2 v1 = __half22float2(*(const __half2*)&hs[s1 * DIM + off]);
                const float2 v2 = __half22float2(*(const __half2*)&hs[s2 * DIM + off]);
                const float2 v3 = __half22float2(*(const __half2*)&hs[s3 * DIM + off]);
                a0.x += v0.x; a0.y += v0.y;
                a1.x += v1.x; a1.y += v1.y;
                a2.x += v2.x; a2.y += v2.y;
                a3.x += v3.x; a3.y += v3.y;
            }
            for (; j < end; ++j) {
                const int s0 = __builtin_amdgcn_readfirstlane(csr[j]);
                const float2 v0 = __half22float2(*(const __half2*)&hs[s0 * DIM + off]);
                a0.x += v0.x; a0.y += v0.y;
            }
            const float dn = dinv[n];
            r.x = fmaxf(fmaf(dn, a0.x + a1.x + a2.x + a3.x, bb.x), 0.f);
            r.y = fmaxf(fmaf(dn, a0.y + a1.y + a2.y + a3.y, bb.y), 0.f);
        }
        *(__half2*)&As[lr][off] = __floats2half2_rn(r.x, r.y);
    }
    __syncthreads();

    // ---- MFMA phase ----
    const int l15  = l & 15;
    const int lk8  = (l >> 4) << 3;
    const int colw = wv << 5;

    f16x8 bf[2][4];
#pragma unroll
    for (int ct = 0; ct < 2; ++ct)
#pragma unroll
        for (int kt = 0; kt < 4; ++kt) {
            const int nn = colw + ct * 16 + l15;
            const int k0 = kt * 32 + lk8;
            f16x8 v;
#pragma unroll
            for (int j = 0; j < 8; ++j) v[j] = (_Float16)W[(k0 + j) * DIM + nn];
            bf[ct][kt] = v;
        }

    f32x4 acc[4][2];
#pragma unroll
    for (int rt = 0; rt < 4; ++rt)
#pragma unroll
        for (int ct = 0; ct < 2; ++ct) acc[rt][ct] = (f32x4){0.f, 0.f, 0.f, 0.f};

#pragma unroll
    for (int rt = 0; rt < 4; ++rt) {
        f16x8 a[4];
#pragma unroll
        for (int kt = 0; kt < 4; ++kt)
            a[kt] = *(const f16x8*)&As[rt * 16 + l15][kt * 32 + lk8];
#pragma unroll
        for (int ct = 0; ct < 2; ++ct)
#pragma unroll
            for (int kt = 0; kt < 4; ++kt)
                acc[rt][ct] = __builtin_amdgcn_mfma_f32_16x16x32_f16(a[kt], bf[ct][kt],
                                                                    acc[rt][ct], 0, 0, 0);
    }

#pragma unroll
    for (int rt = 0; rt < 4; ++rt)
#pragma unroll
        for (int r = 0; r < 4; ++r) {
            const int row = row0 + rt * 16 + ((l >> 4) << 2) + r;
            if (row < NN) {
                const float d = dinv[row];
                outH[row * DIM + colw + l15]      = (_Float16)(acc[rt][0][r] * d);
                outH[row * DIM + colw + 16 + l15] = (_Float16)(acc[rt][1][r] * d);
            }
        }
}

// ---------------- final gather: out = dinv*(sum hs2 rows) + b2 (fp32 out) ----------------
__global__ void k_gather2(const __half* __restrict__ hs, float* __restrict__ outF,
                          const int* __restrict__ csr, const int* __restrict__ rowptr,
                          const float* __restrict__ dinv, const float* __restrict__ b2) {
    const int w = (blockIdx.x * blockDim.x + threadIdx.x) >> 6;
    if (w >= NN) return;
    const int lane = threadIdx.x & 63;
    const int off  = lane << 1;

    const int start = __builtin_amdgcn_readfirstlane(rowptr[w]);
    const int end   = __builtin_amdgcn_readfirstlane(rowptr[w + 1]);

    float2 a0 = __half22float2(*(const __half2*)&hs[w * DIM + off]);  // self-loop
    float2 a1 = {0.f, 0.f}, a2 = {0.f, 0.f}, a3 = {0.f, 0.f};

    int j = start;
    for (; j + 3 < end; j += 4) {
        const int s0 = __builtin_amdgcn_readfirstlane(csr[j]);
        const int s1 = __builtin_amdgcn_readfirstlane(csr[j + 1]);
        const int s2 = __builtin_amdgcn_readfirstlane(csr[j + 2]);
        const int s3 = __builtin_amdgcn_readfirstlane(csr[j + 3]);
        const float2 v0 = __half22float2(*(const __half2*)&hs[s0 * DIM + off]);
        const float2 v1 = __half22float2(*(const __half2*)&hs[s1 * DIM + off]);
        const float2 v2 = __half22float2(*(const __half2*)&hs[s2 * DIM + off]);
        const float2 v3 = __half22float2(*(const __half2*)&hs[s3 * DIM + off]);
        a0.x += v0.x; a0.y += v0.y;
        a1.x += v1.x; a1.y += v1.y;
        a2.x += v2.x; a2.y += v2.y;
        a3.x += v3.x; a3.y += v3.y;
    }
    for (; j < end; ++j) {
        const int s0 = __builtin_amdgcn_readfirstlane(csr[j]);
        const float2 v0 = __half22float2(*(const __half2*)&hs[s0 * DIM + off]);
        a0.x += v0.x; a0.y += v0.y;
    }

    const float d = dinv[w];
    const float2 b = *(const float2*)&b2[off];
    float2 r;
    r.x = fmaf(d, a0.x + a1.x + a2.x + a3.x, b.x);
    r.y = fmaf(d, a0.y + a1.y + a2.y + a3.y, b.y);
    *(float2*)&outF[w * DIM + off] = r;
}

extern "C" void kernel_launch(void* const* d_in, const int* in_sizes, int n_in,
                              void* d_out, int out_size, void* d_ws, size_t ws_size,
                              hipStream_t stream) {
    const float* x  = (const float*)d_in[0];
    const int*   ei = (const int*)d_in[1];
    const float* W1 = (const float*)d_in[2];
    const float* b1 = (const float*)d_in[3];
    const float* W2 = (const float*)d_in[4];
    const float* b2 = (const float*)d_in[5];
    float* out = (float*)d_out;

    const int E = in_sizes[1] / 2;
    const int* src = ei;        // edge_index[0]
    const int* dst = ei + E;    // edge_index[1]

    char* ws = (char*)d_ws;
    float*    dinv   = (float*)(ws);                        // NN floats
    int*      degi   = (int*)  (ws + (1  << 20));           // NN ints
    int*      rowptr = (int*)  (ws + (2  << 20));           // NN+1 ints
    int*      bsum   = (int*)  (ws + (3  << 20));           // NB ints
    int*      bcur   = (int*)  (ws + (3  << 20) + 65536);   // NB ints
    int*      csr    = (int*)  (ws + (4  << 20));           // E ints (6.4 MB)
    int*      binbuf = (int*)  (ws + (11 << 20));           // NB*BCAP ints (8.0 MB)
    _Float16* hs     = (_Float16*)(ws + (20 << 20));        // NN*DIM halfs (25.6 MB)
    _Float16* hs2    = (_Float16*)(ws + (47 << 20));        // NN*DIM halfs (25.6 MB)

    const int ABLK = (E + 4095) / 4096;                     // 391

    // ---- CSR build ----
    k_zero    <<<(NB + 255) / 256, 256, 0, stream>>>(bcur, NB);
    k_binA    <<<ABLK, 256, 0, stream>>>(src, dst, bcur, binbuf, E);
    k_binCount<<<NB, 256, 0, stream>>>(bcur, binbuf, degi, dinv, bsum);
    k_scan2   <<<1, 1024, 0, stream>>>(bsum, NB);

    // ---- layer 1: rowptr-scan + CSR fill (391 blocks) + MFMA GEMM1 (1563 tiles) ----
    k_gemm1<<<NB + GTILES, 256, 0, stream>>>(x, W1, dinv, hs, degi, bsum,
                                             rowptr, bcur, binbuf, csr);

    // ---- gather1 + GEMM2 fused ----
    k_gather_gemm<<<GTILES, 256, 0, stream>>>((const __half*)hs, W2, dinv, b1, hs2,
                                              csr, rowptr);

    // ---- final gather (+ bias) ----
    k_gather2<<<(NN * 64) / 256, 256, 0, stream>>>((const __half*)hs2, out, csr, rowptr,
                                                   dinv, b2);
}